// Round 7
// baseline (336.850 us; speedup 1.0000x reference)
//
#include <hip/hip_runtime.h>

// Problem constants (fixed by the reference):
//   img [8192,1024] f32, txt [8192,1024] f32, both l2-normalized
//   set sizes si=st=4, t=16, tts=1, DENOM=2  -> out[bi][bt] = (right+left)/128
#define N_ROWS 8192
#define DIM    1024
#define BOUT   2048
#define BM 128
#define BN 128
#define BK 32
#define KTILES (DIM / BK)   // 32

typedef unsigned short u16;
typedef __attribute__((ext_vector_type(4))) unsigned short u16x4;
typedef __attribute__((ext_vector_type(8))) short short8;   // 8 bf16 MFMA A/B frag
typedef __attribute__((ext_vector_type(4))) float f32x4;    // MFMA C/D frag
typedef __attribute__((address_space(3))) u16 lds_u16;

// fp32 -> bf16 round-to-nearest-even
__device__ __forceinline__ u16 f2bf(float f) {
  unsigned u = __float_as_uint(f);
  u += 0x7fffu + ((u >> 16) & 1u);
  return (u16)(u >> 16);
}

__global__ void cast_kernel(const float* __restrict__ a, const float* __restrict__ b,
                            u16* __restrict__ oa, u16* __restrict__ ob) {
  const size_t i = ((size_t)blockIdx.x * 256 + threadIdx.x) * 4;
  float4 va = *reinterpret_cast<const float4*>(a + i);
  float4 vb = *reinterpret_cast<const float4*>(b + i);
  u16x4 ua, ub;
  ua[0] = f2bf(va.x); ua[1] = f2bf(va.y); ua[2] = f2bf(va.z); ua[3] = f2bf(va.w);
  ub[0] = f2bf(vb.x); ub[1] = f2bf(vb.y); ub[2] = f2bf(vb.z); ub[3] = f2bf(vb.w);
  *reinterpret_cast<u16x4*>(oa + i) = ua;
  *reinterpret_cast<u16x4*>(ob + i) = ub;
}

// async 16B global->LDS copy (wave-uniform LDS base + lane*16)
__device__ __forceinline__ void async_cp16(const u16* g, u16* l) {
  __builtin_amdgcn_global_load_lds(
      (const __attribute__((address_space(1))) void*)g,
      (__attribute__((address_space(3))) void*)l, 16, 0, 0);
}

// Inline-asm ds_read_b128 (opaque to the LDS-DMA hazard tracker — verified
// +29% in round 3; manual lgkmcnt(0)+sched_barrier before consuming, rule
// #18). OFF is a compile-time byte offset -> `offset:` immediate, so each
// fragment read costs zero address VALU beyond the hoisted base.
template <int OFF>
__device__ __forceinline__ short8 ldsr_o(const lds_u16* p) {
  short8 r;
  if constexpr (OFF == 0)
    asm volatile("ds_read_b128 %0, %1" : "=v"(r) : "v"(p));
  else
    asm volatile("ds_read_b128 %0, %1 offset:%2" : "=v"(r) : "v"(p), "i"(OFF));
  return r;
}

// 128x128 GEMM (NT: A[M,K], B[N,K] row-major, dist = A.B^T), fused smooth-
// chamfer epilogue. Round-7: FRAGMENT-ORDER LDS.
//
// R6 post-mortem: LDS pipe ~57% of wall (16K wave-reads x 12cy + 65K
// conflict-cy/CU from the [row][32] read shape) + VALUBusy 42% (per-read
// address math). Fix: global_load_lds writes linearly at tid*16B, so we pick
// the GLOBAL source of each 16B slot such that LDS holds each MFMA fragment-
// block contiguously: slot s (16B units) = fragment-block (s>>6) x lane
// (s&63); A-block rg holds A[rg*16 + (lane&15)][k = (lane>>4)*8 .. +8] —
// identical per-lane data to the R6-verified read, but now every frag read is
// ds_read_b128 at wave-uniform base + lane*16: each 8-lane quarter touches
// all 32 banks exactly once -> ZERO bank conflicts, and mt/nt offsets are
// compile-time immediates -> ~zero inner-loop VALU.
// 4 waves (2x2), per-wave 64x64 (4x4 tiles of 16x16x32); double-buffered
// 32 KiB LDS; __launch_bounds__(256,4) -> 4 blocks/CU for cross-block
// latency hiding (m114).
__global__ __launch_bounds__(256, 4) void gemm_chamfer(
    const u16* __restrict__ A, const u16* __restrict__ B, float* __restrict__ out) {
  __shared__ __align__(16) u16 lds[2][8192];   // [buf][A 4096 | B 4096] u16 = 32 KiB
  lds_u16* const smb = (lds_u16*)&lds[0][0];
  u16* const lbase = &lds[0][0];

  const int tid  = threadIdx.x;
  const int lane = tid & 63;
  const int wave = tid >> 6;
  const int wm = wave & 1;          // wave row (64 rows)
  const int wn = wave >> 1;         // wave col (64 cols)
  const int lm = lane & 15;
  const int lq = lane >> 4;

  // XCD-aware bijective swizzle: 4096 blocks, 8 XCDs -> 512 consecutive tiles
  // (8 full block-rows) per XCD.
  const int bid = (int)blockIdx.x;
  const int swz = (bid & 7) * 512 + (bid >> 3);
  const int bm0 = (swz >> 6) * BM;
  const int bn0 = (swz & 63) * BN;

  // ---- fragment-order staging sources. Thread t fills slot t (and +256) of
  // A and of B: slot s -> block rg = s>>6, lane ln = s&63;
  // row = rg*16 + (ln&15), k = (ln>>4)*8. For s = t: rg = t>>6, ln = t&63.
  const int srow = ((tid >> 6) * 16) + (tid & 15);   // rows 0..63 (r1: +64)
  const int skol = ((tid >> 4) & 3) * 8;
  const u16* aS = A + (size_t)(bm0 + srow) * DIM + skol;
  const u16* bS = B + (size_t)(bn0 + srow) * DIM + skol;

  // stage K-tile t into buffer bc: A blocks 0-3 / 4-7, B blocks 0-3 / 4-7.
  // LDS dest linear (u16): bc*8192 + tid*8 (+2048 / +4096 / +6144).
#define STAGE(bc, t)                                                          \
  do {                                                                        \
    const int _k = (t) * BK;                                                  \
    u16* _d = lbase + (bc) * 8192 + tid * 8;                                  \
    async_cp16(aS + _k,                    _d);                               \
    async_cp16(aS + _k + (size_t)64 * DIM, _d + 2048);                        \
    async_cp16(bS + _k,                    _d + 4096);                        \
    async_cp16(bS + _k + (size_t)64 * DIM, _d + 6144);                        \
  } while (0)

  f32x4 acc[4][4] = {};
  short8 af[4], bf[4];

  // ---- prologue: tile 0 -> buf 0
  STAGE(0, 0);
  asm volatile("s_waitcnt vmcnt(0)" ::: "memory");
  __builtin_amdgcn_s_barrier();

  // ---- K-loop: one barrier per K-tile; loads for t+1 in flight during the
  // reads+MFMA of t; vmcnt(0) AFTER the MFMA convoy. Race audit: reads of
  // buf[cur] drain at lgkmcnt(0) before the barrier preceding its overwrite;
  // buf[nxt] writes drain at vmcnt(0) before the barrier preceding its reads.
#pragma unroll 2
  for (int t = 0; t < KTILES; ++t) {
    const int cur = (t & 1) * 8192;
    if (t + 1 < KTILES) STAGE((t & 1) ^ 1, t + 1);

    // frag reads: base + lane*16B, mt/nt via offset immediates (1 KiB apart)
    const lds_u16* aP = smb + cur + wm * 2048 + lane * 8;
    const lds_u16* bP = smb + cur + 4096 + wn * 2048 + lane * 8;
    af[0] = ldsr_o<0>(aP);    af[1] = ldsr_o<1024>(aP);
    af[2] = ldsr_o<2048>(aP); af[3] = ldsr_o<3072>(aP);
    bf[0] = ldsr_o<0>(bP);    bf[1] = ldsr_o<1024>(bP);
    bf[2] = ldsr_o<2048>(bP); bf[3] = ldsr_o<3072>(bP);

    asm volatile("s_waitcnt lgkmcnt(0)" ::: "memory");
    __builtin_amdgcn_sched_barrier(0);
    __builtin_amdgcn_s_setprio(1);
#pragma unroll
    for (int mt = 0; mt < 4; ++mt)
#pragma unroll
      for (int nt = 0; nt < 4; ++nt)
        acc[mt][nt] = __builtin_amdgcn_mfma_f32_16x16x32_bf16(af[mt], bf[nt], acc[mt][nt], 0, 0, 0);
    __builtin_amdgcn_s_setprio(0);

    asm volatile("s_waitcnt vmcnt(0)" ::: "memory");
    __builtin_amdgcn_s_barrier();
  }

  // ---- fused chamfer epilogue (verbatim from the verified kernel).
  // C layout: col = lane&15, row = lq*4 + reg; set blocks 4-aligned both dims.
#pragma unroll
  for (int mt = 0; mt < 4; ++mt) {
#pragma unroll
    for (int nt = 0; nt < 4; ++nt) {
      f32x4 c = acc[mt][nt];
      float e0 = __expf(16.0f * c[0]);
      float e1 = __expf(16.0f * c[1]);
      float e2 = __expf(16.0f * c[2]);
      float e3 = __expf(16.0f * c[3]);
      // left partial: log of sum over the 4 img-set rows (in-lane), per column
      float l = __logf(e0 + e1 + e2 + e3);
      // right: per-row sums over the 4 txt-set columns (cross-lane)
      e0 += __shfl_xor(e0, 1); e0 += __shfl_xor(e0, 2);
      e1 += __shfl_xor(e1, 1); e1 += __shfl_xor(e1, 2);
      e2 += __shfl_xor(e2, 1); e2 += __shfl_xor(e2, 2);
      e3 += __shfl_xor(e3, 1); e3 += __shfl_xor(e3, 2);
      float r = __logf(e0) + __logf(e1) + __logf(e2) + __logf(e3);
      // left: sum the per-column logs over the 4 txt-set columns
      l += __shfl_xor(l, 1); l += __shfl_xor(l, 2);
      if ((lane & 3) == 0) {
        const int obi = ((bm0 + wm * 64 + mt * 16) >> 2) + lq;
        const int obt = ((bn0 + wn * 64 + nt * 16) >> 2) + (lm >> 2);
        out[(size_t)obi * BOUT + obt] = (r + l) * 0.0078125f;  // /128
      }
    }
  }
}

extern "C" void kernel_launch(void* const* d_in, const int* in_sizes, int n_in,
                              void* d_out, int out_size, void* d_ws, size_t ws_size,
                              hipStream_t stream) {
  const float* img = (const float*)d_in[0];
  const float* txt = (const float*)d_in[1];
  float* out = (float*)d_out;
  u16* bA = (u16*)d_ws;                       // 16 MiB
  u16* bB = bA + (size_t)N_ROWS * DIM;        // 16 MiB

  const int nPer = N_ROWS * DIM;              // 8388608 per input
  cast_kernel<<<dim3(nPer / (256 * 4)), dim3(256), 0, stream>>>(img, txt, bA, bB);

  dim3 ggrid((N_ROWS / BM) * (N_ROWS / BN));  // 4096 blocks (64x64 tiles)
  gemm_chamfer<<<ggrid, dim3(256), 0, stream>>>(bA, bB, out);
}

// Round 8
// 270.030 us; speedup vs baseline: 1.2475x; 1.2475x over previous
//
#include <hip/hip_runtime.h>

// Problem constants (fixed by the reference):
//   img [8192,1024] f32, txt [8192,1024] f32, both l2-normalized
//   set sizes si=st=4, t=16, tts=1, DENOM=2  -> out[bi][bt] = (right+left)/128
#define N_ROWS 8192
#define DIM    1024
#define BOUT   2048
#define BM 128
#define BN 128
#define BK 32
#define KTILES (DIM / BK)   // 32

typedef unsigned short u16;
typedef __attribute__((ext_vector_type(4))) unsigned short u16x4;
typedef __attribute__((ext_vector_type(8))) short short8;   // 8 bf16 MFMA A/B frag
typedef __attribute__((ext_vector_type(4))) float f32x4;    // MFMA C/D frag
typedef __attribute__((address_space(3))) u16 lds_u16;

// fp32 -> bf16 round-to-nearest-even
__device__ __forceinline__ u16 f2bf(float f) {
  unsigned u = __float_as_uint(f);
  u += 0x7fffu + ((u >> 16) & 1u);
  return (u16)(u >> 16);
}

__global__ void cast_kernel(const float* __restrict__ a, const float* __restrict__ b,
                            u16* __restrict__ oa, u16* __restrict__ ob) {
  const size_t i = ((size_t)blockIdx.x * 256 + threadIdx.x) * 4;
  float4 va = *reinterpret_cast<const float4*>(a + i);
  float4 vb = *reinterpret_cast<const float4*>(b + i);
  u16x4 ua, ub;
  ua[0] = f2bf(va.x); ua[1] = f2bf(va.y); ua[2] = f2bf(va.z); ua[3] = f2bf(va.w);
  ub[0] = f2bf(vb.x); ub[1] = f2bf(vb.y); ub[2] = f2bf(vb.z); ub[3] = f2bf(vb.w);
  *reinterpret_cast<u16x4*>(oa + i) = ua;
  *reinterpret_cast<u16x4*>(ob + i) = ub;
}

// async 16B global->LDS copy (wave-uniform LDS base + lane*16)
__device__ __forceinline__ void async_cp16(const u16* g, u16* l) {
  __builtin_amdgcn_global_load_lds(
      (const __attribute__((address_space(1))) void*)g,
      (__attribute__((address_space(3))) void*)l, 16, 0, 0);
}

// Inline-asm ds_read_b128 (opaque to the LDS-DMA hazard tracker — verified
// +29% in round 3; manual lgkmcnt(0)+sched_barrier before consuming, rule
// #18). OFF = compile-time byte offset -> `offset:` immediate (zero address
// VALU beyond the hoisted base).
template <int OFF>
__device__ __forceinline__ short8 ldsr_o(const lds_u16* p) {
  short8 r;
  if constexpr (OFF == 0)
    asm volatile("ds_read_b128 %0, %1" : "=v"(r) : "v"(p));
  else
    asm volatile("ds_read_b128 %0, %1 offset:%2" : "=v"(r) : "v"(p), "i"(OFF));
  return r;
}

// 128x128 GEMM (NT: A[M,K], B[N,K] row-major, dist = A.B^T), fused smooth-
// chamfer epilogue. Round-8: R6 structure + CHUNK SWIZZLE on both sides.
//
// R6/R7 pair isolated the tradeoff: R6 = coalesced staging but 8-lane-batch
// LDS conflicts (1.678e7 = ~4 cy/read = 14% of wall) + 42% VALU addr math;
// R7 = conflict-free reads but scattered 16B global gathers (HBM 2.8->2.0
// TB/s, worse). R8 keeps R6's staging geometry (row t>>2, 64B contiguous
// per row, linear LDS dest = tid*16B) and stores chunk c of row r at
// physical chunk c ^ ((r>>1)&3), by pre-XOR-ing the GLOBAL source column.
// Conflict model (calibrated by R7's zero): a read's 16B-slot =
// (r&1)*4 + pchunk; with pchunk = lq ^ ((r>>1)&3) every aligned 8-lane
// group covers all 8 slots exactly once (enumerated for all 4 lq groups)
// -> conflict-free. Swizzle term is mt-invariant so reads are 2 base
// pointers + offset immediates. Coalescing unchanged (chunks permuted
// WITHIN each 64B row segment).
// 4 waves (2x2), per-wave 64x64 (4x4 of 16x16x32); double-buffered 32 KiB
// LDS; __launch_bounds__(256,4) -> 4 blocks/CU (m114 cross-block hiding).
__global__ __launch_bounds__(256, 4) void gemm_chamfer(
    const u16* __restrict__ A, const u16* __restrict__ B, float* __restrict__ out) {
  __shared__ __align__(16) u16 lds[2][8192];   // [buf][A 4096 | B 4096] u16 = 32 KiB
  lds_u16* const smb = (lds_u16*)&lds[0][0];
  u16* const lbase = &lds[0][0];

  const int tid  = threadIdx.x;
  const int lane = tid & 63;
  const int wave = tid >> 6;
  const int wm = wave & 1;          // wave row (64 rows)
  const int wn = wave >> 1;         // wave col (64 cols)
  const int lm = lane & 15;
  const int lq = lane >> 4;

  // XCD-aware bijective swizzle: 4096 blocks, 8 XCDs -> 512 consecutive tiles
  // (8 full block-rows) per XCD.
  const int bid = (int)blockIdx.x;
  const int swz = (bid & 7) * 512 + (bid >> 3);
  const int bm0 = (swz >> 6) * BM;
  const int bn0 = (swz & 63) * BN;

  // staging map: thread t -> row t>>2 (and +64), physical chunk t&3.
  // Source column = logical chunk = (t&3) ^ ((row>>1)&3) (involution), so
  // LDS[row][pc] holds logical chunk pc ^ ((row>>1)&3). Dest = tid*16B linear.
  const int ldrow = tid >> 2;
  const int ldk   = (((tid & 3) ^ ((ldrow >> 1) & 3)) * 8);
  const u16* aSrc = A + (size_t)(bm0 + ldrow) * DIM + ldk;
  const u16* bSrc = B + (size_t)(bn0 + ldrow) * DIM + ldk;
  const size_t half = (size_t)64 * DIM;

  // stage K-tile t into buffer bc (u16 offsets: buf stride 8192; A rows
  // 64..127 at +2048; B region at +4096)
#define STAGE(bc, t)                                                          \
  do {                                                                        \
    const int _k = (t) * BK;                                                  \
    u16* _la = lbase + (bc) * 8192 + tid * 8;                                 \
    async_cp16(aSrc + _k,        _la);                                        \
    async_cp16(aSrc + _k + half, _la + 2048);                                 \
    async_cp16(bSrc + _k,        _la + 4096);                                 \
    async_cp16(bSrc + _k + half, _la + 6144);                                 \
  } while (0)

  // fragment-read bases: row = (wm|wn)*64 + mt*16 + lm; physical chunk =
  // lq ^ ((row>>1)&3) = lq ^ ((lm>>1)&3)  (mt*16, w*64 ≡ 0 mod 4 after >>1).
  // mt offsets = mt*16 rows * 64B = 1024B immediates.
  const int pck = (lq ^ ((lm >> 1) & 3)) * 8;
  const int aFrag = wm * 2048 + lm * BK + pck;
  const int bFrag = 4096 + wn * 2048 + lm * BK + pck;

  f32x4 acc[4][4] = {};
  short8 af[4], bf[4];

  // ---- prologue: tile 0 -> buf 0
  STAGE(0, 0);
  asm volatile("s_waitcnt vmcnt(0)" ::: "memory");
  __builtin_amdgcn_s_barrier();

  // ---- K-loop (sync structure identical to R6-passed): one barrier per
  // K-tile; loads for t+1 in flight during reads+MFMA of t; vmcnt(0) after
  // the MFMA convoy. Race audit: reads of buf[cur] drain at lgkmcnt(0)
  // before the barrier preceding its overwrite; buf[nxt] writes drain at
  // vmcnt(0) before the barrier preceding its reads.
#pragma unroll 2
  for (int t = 0; t < KTILES; ++t) {
    const int cur = (t & 1) * 8192;
    if (t + 1 < KTILES) STAGE((t & 1) ^ 1, t + 1);

    const lds_u16* aP = smb + cur + aFrag;
    const lds_u16* bP = smb + cur + bFrag;
    af[0] = ldsr_o<0>(aP);    af[1] = ldsr_o<1024>(aP);
    af[2] = ldsr_o<2048>(aP); af[3] = ldsr_o<3072>(aP);
    bf[0] = ldsr_o<0>(bP);    bf[1] = ldsr_o<1024>(bP);
    bf[2] = ldsr_o<2048>(bP); bf[3] = ldsr_o<3072>(bP);

    asm volatile("s_waitcnt lgkmcnt(0)" ::: "memory");
    __builtin_amdgcn_sched_barrier(0);
    __builtin_amdgcn_s_setprio(1);
#pragma unroll
    for (int mt = 0; mt < 4; ++mt)
#pragma unroll
      for (int nt = 0; nt < 4; ++nt)
        acc[mt][nt] = __builtin_amdgcn_mfma_f32_16x16x32_bf16(af[mt], bf[nt], acc[mt][nt], 0, 0, 0);
    __builtin_amdgcn_s_setprio(0);

    asm volatile("s_waitcnt vmcnt(0)" ::: "memory");
    __builtin_amdgcn_s_barrier();
  }

  // ---- fused chamfer epilogue (verbatim from the verified kernel).
  // C layout: col = lane&15, row = lq*4 + reg; set blocks 4-aligned both dims.
#pragma unroll
  for (int mt = 0; mt < 4; ++mt) {
#pragma unroll
    for (int nt = 0; nt < 4; ++nt) {
      f32x4 c = acc[mt][nt];
      float e0 = __expf(16.0f * c[0]);
      float e1 = __expf(16.0f * c[1]);
      float e2 = __expf(16.0f * c[2]);
      float e3 = __expf(16.0f * c[3]);
      // left partial: log of sum over the 4 img-set rows (in-lane), per column
      float l = __logf(e0 + e1 + e2 + e3);
      // right: per-row sums over the 4 txt-set columns (cross-lane)
      e0 += __shfl_xor(e0, 1); e0 += __shfl_xor(e0, 2);
      e1 += __shfl_xor(e1, 1); e1 += __shfl_xor(e1, 2);
      e2 += __shfl_xor(e2, 1); e2 += __shfl_xor(e2, 2);
      e3 += __shfl_xor(e3, 1); e3 += __shfl_xor(e3, 2);
      float r = __logf(e0) + __logf(e1) + __logf(e2) + __logf(e3);
      // left: sum the per-column logs over the 4 txt-set columns
      l += __shfl_xor(l, 1); l += __shfl_xor(l, 2);
      if ((lane & 3) == 0) {
        const int obi = ((bm0 + wm * 64 + mt * 16) >> 2) + lq;
        const int obt = ((bn0 + wn * 64 + nt * 16) >> 2) + (lm >> 2);
        out[(size_t)obi * BOUT + obt] = (r + l) * 0.0078125f;  // /128
      }
    }
  }
}

extern "C" void kernel_launch(void* const* d_in, const int* in_sizes, int n_in,
                              void* d_out, int out_size, void* d_ws, size_t ws_size,
                              hipStream_t stream) {
  const float* img = (const float*)d_in[0];
  const float* txt = (const float*)d_in[1];
  float* out = (float*)d_out;
  u16* bA = (u16*)d_ws;                       // 16 MiB
  u16* bB = bA + (size_t)N_ROWS * DIM;        // 16 MiB

  const int nPer = N_ROWS * DIM;              // 8388608 per input
  cast_kernel<<<dim3(nPer / (256 * 4)), dim3(256), 0, stream>>>(img, txt, bA, bB);

  dim3 ggrid((N_ROWS / BM) * (N_ROWS / BN));  // 4096 blocks (64x64 tiles)
  gemm_chamfer<<<ggrid, dim3(256), 0, stream>>>(bA, bB, out);
}

// Round 9
// 268.122 us; speedup vs baseline: 1.2563x; 1.0071x over previous
//
#include <hip/hip_runtime.h>

// Problem constants (fixed by the reference):
//   img [8192,1024] f32, txt [8192,1024] f32, both l2-normalized
//   set sizes si=st=4, t=16, tts=1, DENOM=2  -> out[bi][bt] = (right+left)/128
#define N_ROWS 8192
#define DIM    1024
#define BOUT   2048
#define BM 128
#define BN 128
#define BK 32
#define KTILES (DIM / BK)   // 32

typedef unsigned short u16;
typedef __attribute__((ext_vector_type(4))) unsigned short u16x4;
typedef __attribute__((ext_vector_type(8))) short short8;   // 8 bf16 MFMA A/B frag
typedef __attribute__((ext_vector_type(4))) float f32x4;    // MFMA C/D frag
typedef __attribute__((address_space(3))) u16 lds_u16;

// fp32 -> bf16 round-to-nearest-even
__device__ __forceinline__ u16 f2bf(float f) {
  unsigned u = __float_as_uint(f);
  u += 0x7fffu + ((u >> 16) & 1u);
  return (u16)(u >> 16);
}

__global__ void cast_kernel(const float* __restrict__ a, const float* __restrict__ b,
                            u16* __restrict__ oa, u16* __restrict__ ob) {
  const size_t i = ((size_t)blockIdx.x * 256 + threadIdx.x) * 4;
  float4 va = *reinterpret_cast<const float4*>(a + i);
  float4 vb = *reinterpret_cast<const float4*>(b + i);
  u16x4 ua, ub;
  ua[0] = f2bf(va.x); ua[1] = f2bf(va.y); ua[2] = f2bf(va.z); ua[3] = f2bf(va.w);
  ub[0] = f2bf(vb.x); ub[1] = f2bf(vb.y); ub[2] = f2bf(vb.z); ub[3] = f2bf(vb.w);
  *reinterpret_cast<u16x4*>(oa + i) = ua;
  *reinterpret_cast<u16x4*>(ob + i) = ub;
}

// async 16B global->LDS copy (wave-uniform LDS base + lane*16)
__device__ __forceinline__ void async_cp16(const u16* g, u16* l) {
  __builtin_amdgcn_global_load_lds(
      (const __attribute__((address_space(1))) void*)g,
      (__attribute__((address_space(3))) void*)l, 16, 0, 0);
}

// Inline-asm ds_read_b128 (opaque to the LDS-DMA hazard tracker — verified
// +29% in round 3; manual lgkmcnt(0)+sched_barrier before consuming, rule
// #18). OFF = compile-time byte offset -> `offset:` immediate.
template <int OFF>
__device__ __forceinline__ short8 ldsr_o(const lds_u16* p) {
  short8 r;
  if constexpr (OFF == 0)
    asm volatile("ds_read_b128 %0, %1" : "=v"(r) : "v"(p));
  else
    asm volatile("ds_read_b128 %0, %1 offset:%2" : "=v"(r) : "v"(p), "i"(OFF));
  return r;
}

// 128x128 GEMM (NT: A[M,K], B[N,K] row-major, dist = A.B^T), fused smooth-
// chamfer epilogue. Round-9: R8 (conflict-free chunk swizzle, verified
// SQ_LDS_BANK_CONFLICT=0) + COUNTED vmcnt VIA 3-BUFFER / 2-TILE PREFETCH.
//
// R8 post-mortem: removing conflicts didn't move time -> they were hidden
// under a larger stall. The remaining structural stall is the per-iteration
// `vmcnt(0)`: with 2 buffers, tile t+1's stage loads must land in the same
// iteration (~300-400 cy window), but FETCH 504 MB/dispatch => most staging
// misses L2 (HBM latency ~900 cy, m126) -> ~300-500 cy exposed per iter.
// T4 fix: 3 buffers, iter t stages tile t+2 and waits vmcnt(4) (tile t+1
// landed; t+2's 4 loads stay in flight ACROSS the barrier) -> full-iteration
// latency window. Race audit: the buffer overwritten at iter t was read at
// iter t-1 (lgkmcnt(0) + end-barrier precede overwrite); staged writes land
// by vmcnt(4) at iter t+1's end, barrier before their reads at t+2. Tail:
// t=KT-2 -> vmcnt(0).
// 4 waves (2x2), per-wave 64x64 (4x4 of 16x16x32); 3 x 16 KiB LDS ->
// __launch_bounds__(256,3), 3 blocks/CU.
__global__ __launch_bounds__(256, 3) void gemm_chamfer(
    const u16* __restrict__ A, const u16* __restrict__ B, float* __restrict__ out) {
  __shared__ __align__(16) u16 lds[3][8192];   // [buf][A 4096 | B 4096] u16 = 48 KiB
  lds_u16* const smb = (lds_u16*)&lds[0][0];
  u16* const lbase = &lds[0][0];

  const int tid  = threadIdx.x;
  const int lane = tid & 63;
  const int wave = tid >> 6;
  const int wm = wave & 1;          // wave row (64 rows)
  const int wn = wave >> 1;         // wave col (64 cols)
  const int lm = lane & 15;
  const int lq = lane >> 4;

  // XCD-aware bijective swizzle: 4096 blocks, 8 XCDs -> 512 consecutive tiles
  // (8 full block-rows) per XCD.
  const int bid = (int)blockIdx.x;
  const int swz = (bid & 7) * 512 + (bid >> 3);
  const int bm0 = (swz >> 6) * BM;
  const int bn0 = (swz & 63) * BN;

  // staging map (R8-verified): thread t -> row t>>2 (and +64), physical chunk
  // t&3; source column = (t&3) ^ ((row>>1)&3) (involution) so LDS[row][pc]
  // holds logical chunk pc ^ ((row>>1)&3). Dest = tid*16B linear.
  const int ldrow = tid >> 2;
  const int ldk   = (((tid & 3) ^ ((ldrow >> 1) & 3)) * 8);
  const u16* aSrc = A + (size_t)(bm0 + ldrow) * DIM + ldk;
  const u16* bSrc = B + (size_t)(bn0 + ldrow) * DIM + ldk;
  const size_t half = (size_t)64 * DIM;

  // stage K-tile t into buffer at u16 offset bufo (A rows 64..127 at +2048;
  // B region at +4096)
#define STAGE(bufo, t)                                                        \
  do {                                                                        \
    const int _k = (t) * BK;                                                  \
    u16* _la = lbase + (bufo) + tid * 8;                                      \
    async_cp16(aSrc + _k,        _la);                                        \
    async_cp16(aSrc + _k + half, _la + 2048);                                 \
    async_cp16(bSrc + _k,        _la + 4096);                                 \
    async_cp16(bSrc + _k + half, _la + 6144);                                 \
  } while (0)

  // fragment-read bases (R8-verified, conflict-free): physical chunk =
  // lq ^ ((lm>>1)&3); mt/nt offsets are 1024B immediates.
  const int pck = (lq ^ ((lm >> 1) & 3)) * 8;
  const int aFrag = wm * 2048 + lm * BK + pck;
  const int bFrag = 4096 + wn * 2048 + lm * BK + pck;

  f32x4 acc[4][4] = {};
  short8 af[4], bf[4];

  // ---- prologue: tiles 0,1 -> bufs 0,1; vmcnt(4) = tile 0 landed, tile 1's
  // 4 loads remain in flight across the barrier.
  int cur = 0, nxt = 8192, nx2 = 16384;   // rotating u16 buffer offsets
  STAGE(cur, 0);
  STAGE(nxt, 1);
  asm volatile("s_waitcnt vmcnt(4)" ::: "memory");
  __builtin_amdgcn_s_barrier();

  // ---- K-loop: one barrier per K-tile; 2-tile prefetch depth; counted
  // vmcnt(4) in steady state (never 0 until the tail).
  for (int t = 0; t < KTILES; ++t) {
    if (t + 2 < KTILES) STAGE(nx2, t + 2);

    const lds_u16* aP = smb + cur + aFrag;
    const lds_u16* bP = smb + cur + bFrag;
    af[0] = ldsr_o<0>(aP);    af[1] = ldsr_o<1024>(aP);
    af[2] = ldsr_o<2048>(aP); af[3] = ldsr_o<3072>(aP);
    bf[0] = ldsr_o<0>(bP);    bf[1] = ldsr_o<1024>(bP);
    bf[2] = ldsr_o<2048>(bP); bf[3] = ldsr_o<3072>(bP);

    asm volatile("s_waitcnt lgkmcnt(0)" ::: "memory");
    __builtin_amdgcn_sched_barrier(0);
    __builtin_amdgcn_s_setprio(1);
#pragma unroll
    for (int mt = 0; mt < 4; ++mt)
#pragma unroll
      for (int nt = 0; nt < 4; ++nt)
        acc[mt][nt] = __builtin_amdgcn_mfma_f32_16x16x32_bf16(af[mt], bf[nt], acc[mt][nt], 0, 0, 0);
    __builtin_amdgcn_s_setprio(0);

    // steady state: tile t+1 landed (oldest 4 of 8 outstanding); tile t+2's
    // 4 loads stay in flight across the barrier. Tail (t>=KT-2): drain.
    if (t + 2 < KTILES) asm volatile("s_waitcnt vmcnt(4)" ::: "memory");
    else                asm volatile("s_waitcnt vmcnt(0)" ::: "memory");
    __builtin_amdgcn_s_barrier();

    const int tmp = cur; cur = nxt; nxt = nx2; nx2 = tmp;
  }

  // ---- fused chamfer epilogue (verbatim from the verified kernel).
  // C layout: col = lane&15, row = lq*4 + reg; set blocks 4-aligned both dims.
#pragma unroll
  for (int mt = 0; mt < 4; ++mt) {
#pragma unroll
    for (int nt = 0; nt < 4; ++nt) {
      f32x4 c = acc[mt][nt];
      float e0 = __expf(16.0f * c[0]);
      float e1 = __expf(16.0f * c[1]);
      float e2 = __expf(16.0f * c[2]);
      float e3 = __expf(16.0f * c[3]);
      // left partial: log of sum over the 4 img-set rows (in-lane), per column
      float l = __logf(e0 + e1 + e2 + e3);
      // right: per-row sums over the 4 txt-set columns (cross-lane)
      e0 += __shfl_xor(e0, 1); e0 += __shfl_xor(e0, 2);
      e1 += __shfl_xor(e1, 1); e1 += __shfl_xor(e1, 2);
      e2 += __shfl_xor(e2, 1); e2 += __shfl_xor(e2, 2);
      e3 += __shfl_xor(e3, 1); e3 += __shfl_xor(e3, 2);
      float r = __logf(e0) + __logf(e1) + __logf(e2) + __logf(e3);
      // left: sum the per-column logs over the 4 txt-set columns
      l += __shfl_xor(l, 1); l += __shfl_xor(l, 2);
      if ((lane & 3) == 0) {
        const int obi = ((bm0 + wm * 64 + mt * 16) >> 2) + lq;
        const int obt = ((bn0 + wn * 64 + nt * 16) >> 2) + (lm >> 2);
        out[(size_t)obi * BOUT + obt] = (r + l) * 0.0078125f;  // /128
      }
    }
  }
}

extern "C" void kernel_launch(void* const* d_in, const int* in_sizes, int n_in,
                              void* d_out, int out_size, void* d_ws, size_t ws_size,
                              hipStream_t stream) {
  const float* img = (const float*)d_in[0];
  const float* txt = (const float*)d_in[1];
  float* out = (float*)d_out;
  u16* bA = (u16*)d_ws;                       // 16 MiB
  u16* bB = bA + (size_t)N_ROWS * DIM;        // 16 MiB

  const int nPer = N_ROWS * DIM;              // 8388608 per input
  cast_kernel<<<dim3(nPer / (256 * 4)), dim3(256), 0, stream>>>(img, txt, bA, bB);

  dim3 ggrid((N_ROWS / BM) * (N_ROWS / BN));  // 4096 blocks (64x64 tiles)
  gemm_chamfer<<<ggrid, dim3(256), 0, stream>>>(bA, bB, out);
}

// Round 10
// 264.383 us; speedup vs baseline: 1.2741x; 1.0141x over previous
//
#include <hip/hip_runtime.h>

// Problem constants (fixed by the reference):
//   img [8192,1024] f32, txt [8192,1024] f32, both l2-normalized
//   set sizes si=st=4, t=16, tts=1, DENOM=2  -> out[bi][bt] = (right+left)/128
#define N_ROWS 8192
#define DIM    1024
#define BOUT   2048
#define BM 128
#define BN 128
#define BK 32
#define KTILES 32
// rotating triple-buffer u16 offsets (16 KiB each: A 4096 | B 4096)
#define C0 0
#define C1 8192
#define C2 16384

typedef unsigned short u16;
typedef __attribute__((ext_vector_type(4))) unsigned short u16x4;
typedef __attribute__((ext_vector_type(8))) short short8;   // 8 bf16 MFMA A/B frag
typedef __attribute__((ext_vector_type(4))) float f32x4;    // MFMA C/D frag
typedef __attribute__((address_space(3))) u16 lds_u16;

// fp32 -> bf16 round-to-nearest-even
__device__ __forceinline__ u16 f2bf(float f) {
  unsigned u = __float_as_uint(f);
  u += 0x7fffu + ((u >> 16) & 1u);
  return (u16)(u >> 16);
}

__global__ void cast_kernel(const float* __restrict__ a, const float* __restrict__ b,
                            u16* __restrict__ oa, u16* __restrict__ ob) {
  const size_t i = ((size_t)blockIdx.x * 256 + threadIdx.x) * 4;
  float4 va = *reinterpret_cast<const float4*>(a + i);
  float4 vb = *reinterpret_cast<const float4*>(b + i);
  u16x4 ua, ub;
  ua[0] = f2bf(va.x); ua[1] = f2bf(va.y); ua[2] = f2bf(va.z); ua[3] = f2bf(va.w);
  ub[0] = f2bf(vb.x); ub[1] = f2bf(vb.y); ub[2] = f2bf(vb.z); ub[3] = f2bf(vb.w);
  *reinterpret_cast<u16x4*>(oa + i) = ua;
  *reinterpret_cast<u16x4*>(ob + i) = ub;
}

// async 16B global->LDS copy (wave-uniform LDS base + lane*16)
__device__ __forceinline__ void async_cp16(const u16* g, u16* l) {
  __builtin_amdgcn_global_load_lds(
      (const __attribute__((address_space(1))) void*)g,
      (__attribute__((address_space(3))) void*)l, 16, 0, 0);
}

// Inline-asm ds_read_b128 (opaque to the LDS-DMA hazard tracker — verified
// +29% in round 3). OFF = compile-time byte offset -> `offset:` immediate
// (16-bit unsigned; max used ~49K < 65536). All ordering manual per rule #18.
template <int OFF>
__device__ __forceinline__ short8 ldsr_o(const lds_u16* p) {
  short8 r;
  if constexpr (OFF == 0)
    asm volatile("ds_read_b128 %0, %1" : "=v"(r) : "v"(p));
  else
    asm volatile("ds_read_b128 %0, %1 offset:%2" : "=v"(r) : "v"(p), "i"(OFF));
  return r;
}

#define MM(a, b, c) __builtin_amdgcn_mfma_f32_16x16x32_bf16((a), (b), (c), 0, 0, 0)

// counted lgkm wait + scheduling fence (rule #18: compiler may hoist
// register-only MFMA past inline-asm waitcnt without the sched_barrier)
#define WT(N)                                                                 \
  do {                                                                        \
    asm volatile("s_waitcnt lgkmcnt(" #N ")" ::: "memory");                   \
    __builtin_amdgcn_sched_barrier(0);                                        \
  } while (0)

#define MFC(nt)                                                               \
  do {                                                                        \
    acc[0][nt] = MM(af[0], bf[nt], acc[0][nt]);                               \
    acc[1][nt] = MM(af[1], bf[nt], acc[1][nt]);                               \
    acc[2][nt] = MM(af[2], bf[nt], acc[2][nt]);                               \
    acc[3][nt] = MM(af[3], bf[nt], acc[3][nt]);                               \
  } while (0)

// One K-tile iteration. Reads buf CUR (u16 off), optionally stages the tile
// at group-pointer+KOFF into buf NX, ends with vmcnt(VMT)+barrier.
// Read issue order bf0,af0..3,bf1,bf2,bf3 (DS retires in order) lets the
// first MFMA fire at lgkmcnt(6) — ~2 read-latencies instead of 8.
// Per-element accumulation order is unchanged (column-major over acc cells).
#define ITER(CUR, NX, DO_STAGE, KOFF, VMT)                                    \
  do {                                                                        \
    bf[0] = ldsr_o<(CUR)*2 +    0>(bB);                                       \
    af[0] = ldsr_o<(CUR)*2 +    0>(aB);                                       \
    af[1] = ldsr_o<(CUR)*2 + 1024>(aB);                                       \
    af[2] = ldsr_o<(CUR)*2 + 2048>(aB);                                       \
    af[3] = ldsr_o<(CUR)*2 + 3072>(aB);                                       \
    bf[1] = ldsr_o<(CUR)*2 + 1024>(bB);                                       \
    bf[2] = ldsr_o<(CUR)*2 + 2048>(bB);                                       \
    bf[3] = ldsr_o<(CUR)*2 + 3072>(bB);                                       \
    if (DO_STAGE) {                                                           \
      u16* _d = lbase + (NX) + tid * 8;                                       \
      async_cp16(aLo + (KOFF), _d);                                           \
      async_cp16(aHi + (KOFF), _d + 2048);                                    \
      async_cp16(bLo + (KOFF), _d + 4096);                                    \
      async_cp16(bHi + (KOFF), _d + 6144);                                    \
    }                                                                         \
    __builtin_amdgcn_s_setprio(1);                                            \
    WT(6); acc[0][0] = MM(af[0], bf[0], acc[0][0]);                           \
    WT(5); acc[1][0] = MM(af[1], bf[0], acc[1][0]);                           \
    WT(4); acc[2][0] = MM(af[2], bf[0], acc[2][0]);                           \
    WT(3); acc[3][0] = MM(af[3], bf[0], acc[3][0]);                           \
    WT(2); MFC(1);                                                            \
    WT(1); MFC(2);                                                            \
    WT(0); MFC(3);                                                            \
    __builtin_amdgcn_s_setprio(0);                                            \
    asm volatile("s_waitcnt vmcnt(" #VMT ")" ::: "memory");                   \
    __builtin_amdgcn_s_barrier();                                             \
  } while (0)

// 128x128 GEMM (NT: A[M,K], B[N,K] row-major, dist = A.B^T), fused smooth-
// chamfer epilogue. Round-10: R9 (conflict-free swizzle + 3-buffer counted
// vmcnt, both verified) + COUNTED-LGKM READ->MFMA INTERLEAVE + VALU DIET
// (rotation unrolled x3 -> all LDS offsets are compile-time immediates off
// two loop-invariant base VGPRs; staging via 4 pointer-bumped bases).
// Tile X lives in buf[X%3]; iter t reads buf[t%3], stages tile t+2 into
// buf[(t+2)%3]. vmcnt(4) steady / 0 at tail (audited R9). Reads of CUR all
// retired at WT(0) before the end barrier; the buffer is overwritten at
// iter t+1 (after that barrier) and its writes verified landed by the
// vmcnt(4) at end of iter t+2, barrier before reads at t+3.
__global__ __launch_bounds__(256, 3) void gemm_chamfer(
    const u16* __restrict__ A, const u16* __restrict__ B, float* __restrict__ out) {
  __shared__ __align__(16) u16 lds[3][8192];   // 48 KiB
  lds_u16* const smb = (lds_u16*)&lds[0][0];
  u16* const lbase = &lds[0][0];

  const int tid  = threadIdx.x;
  const int lane = tid & 63;
  const int wave = tid >> 6;
  const int wm = wave & 1;          // wave row (64 rows)
  const int wn = wave >> 1;         // wave col (64 cols)
  const int lm = lane & 15;
  const int lq = lane >> 4;

  // XCD-aware bijective swizzle: 4096 blocks, 8 XCDs -> 512 consecutive
  // tiles (8 full block-rows) per XCD.
  const int bid = (int)blockIdx.x;
  const int swz = (bid & 7) * 512 + (bid >> 3);
  const int bm0 = (swz >> 6) * BM;
  const int bn0 = (swz & 63) * BN;

  // staging map (R8-verified conflict-free): thread t -> row t>>2 (and +64),
  // physical chunk t&3; source column = (t&3) ^ ((row>>1)&3) (involution).
  // LDS dest = tid*16B linear.
  const int ldrow = tid >> 2;
  const int ldk   = (((tid & 3) ^ ((ldrow >> 1) & 3)) * 8);
  const u16* aSrc = A + (size_t)(bm0 + ldrow) * DIM + ldk;
  const u16* bSrc = B + (size_t)(bn0 + ldrow) * DIM + ldk;
  const size_t half = (size_t)64 * DIM;

  // fragment-read bases (R8-verified, SQ_LDS_BANK_CONFLICT=0): physical
  // chunk = lq ^ ((lm>>1)&3); mt offsets = 1024B immediates; buffer offsets
  // folded into the ds_read offset immediate (compile-time via unroll-3).
  const int pck = (lq ^ ((lm >> 1) & 3)) * 8;
  const lds_u16* aB = smb + wm * 2048 + lm * BK + pck;
  const lds_u16* bB = smb + 4096 + wn * 2048 + lm * BK + pck;

  f32x4 acc[4][4] = {};
  short8 af[4], bf[4];

  // ---- prologue: tiles 0,1 -> bufs 0,1; vmcnt(4) = tile 0 landed, tile 1's
  // 4 loads in flight across the barrier.
  {
    u16* _d0 = lbase + tid * 8;
    async_cp16(aSrc,        _d0);
    async_cp16(aSrc + half, _d0 + 2048);
    async_cp16(bSrc,        _d0 + 4096);
    async_cp16(bSrc + half, _d0 + 6144);
    u16* _d1 = lbase + C1 + tid * 8;
    async_cp16(aSrc + BK,        _d1);
    async_cp16(aSrc + BK + half, _d1 + 2048);
    async_cp16(bSrc + BK,        _d1 + 4096);
    async_cp16(bSrc + BK + half, _d1 + 6144);
  }
  asm volatile("s_waitcnt vmcnt(4)" ::: "memory");
  __builtin_amdgcn_s_barrier();

  // ---- K-loop: 10 groups of 3 (t=0..29, staging tiles 2..31), 2 tail iters.
  const u16* aLo = aSrc + 2 * BK;
  const u16* aHi = aSrc + 2 * BK + half;
  const u16* bLo = bSrc + 2 * BK;
  const u16* bHi = bSrc + 2 * BK + half;
  for (int tt = 0; tt < 30; tt += 3) {
    ITER(C0, C2, 1, 0,      4);
    ITER(C1, C0, 1, BK,     4);
    ITER(C2, C1, 1, 2 * BK, 4);
    aLo += 3 * BK; aHi += 3 * BK; bLo += 3 * BK; bHi += 3 * BK;
  }
  ITER(C0, C1, 0, 0, 0);   // t=30 (tile 31's loads drained here)
  ITER(C1, C2, 0, 0, 0);   // t=31

  // ---- fused chamfer epilogue (verbatim from the verified kernel).
  // C layout: col = lane&15, row = lq*4 + reg; set blocks 4-aligned both dims.
#pragma unroll
  for (int mt = 0; mt < 4; ++mt) {
#pragma unroll
    for (int nt = 0; nt < 4; ++nt) {
      f32x4 c = acc[mt][nt];
      float e0 = __expf(16.0f * c[0]);
      float e1 = __expf(16.0f * c[1]);
      float e2 = __expf(16.0f * c[2]);
      float e3 = __expf(16.0f * c[3]);
      // left partial: log of sum over the 4 img-set rows (in-lane), per column
      float l = __logf(e0 + e1 + e2 + e3);
      // right: per-row sums over the 4 txt-set columns (cross-lane)
      e0 += __shfl_xor(e0, 1); e0 += __shfl_xor(e0, 2);
      e1 += __shfl_xor(e1, 1); e1 += __shfl_xor(e1, 2);
      e2 += __shfl_xor(e2, 1); e2 += __shfl_xor(e2, 2);
      e3 += __shfl_xor(e3, 1); e3 += __shfl_xor(e3, 2);
      float r = __logf(e0) + __logf(e1) + __logf(e2) + __logf(e3);
      // left: sum the per-column logs over the 4 txt-set columns
      l += __shfl_xor(l, 1); l += __shfl_xor(l, 2);
      if ((lane & 3) == 0) {
        const int obi = ((bm0 + wm * 64 + mt * 16) >> 2) + lq;
        const int obt = ((bn0 + wn * 64 + nt * 16) >> 2) + (lm >> 2);
        out[(size_t)obi * BOUT + obt] = (r + l) * 0.0078125f;  // /128
      }
    }
  }
}

extern "C" void kernel_launch(void* const* d_in, const int* in_sizes, int n_in,
                              void* d_out, int out_size, void* d_ws, size_t ws_size,
                              hipStream_t stream) {
  const float* img = (const float*)d_in[0];
  const float* txt = (const float*)d_in[1];
  float* out = (float*)d_out;
  u16* bA = (u16*)d_ws;                       // 16 MiB
  u16* bB = bA + (size_t)N_ROWS * DIM;        // 16 MiB

  const int nPer = N_ROWS * DIM;              // 8388608 per input
  cast_kernel<<<dim3(nPer / (256 * 4)), dim3(256), 0, stream>>>(img, txt, bA, bB);

  dim3 ggrid((N_ROWS / BM) * (N_ROWS / BN));  // 4096 blocks (64x64 tiles)
  gemm_chamfer<<<ggrid, dim3(256), 0, stream>>>(bA, bB, out);
}